// Round 17
// baseline (743.737 us; speedup 1.0000x reference)
//
#include <hip/hip_runtime.h>
#include <math.h>

typedef __attribute__((ext_vector_type(8))) short short8;
typedef __attribute__((ext_vector_type(8))) _Float16 f16x8;
typedef __attribute__((ext_vector_type(4))) float f32x4;
typedef __attribute__((ext_vector_type(4))) unsigned uint32x4;

__device__ __forceinline__ void split_f16(float f, unsigned short& h, unsigned short& l){
  _Float16 hh = (_Float16)f;
  _Float16 ll = (_Float16)(f - (float)hh);
  h = __builtin_bit_cast(unsigned short, hh);
  l = __builtin_bit_cast(unsigned short, ll);
}

__device__ __forceinline__ float fsig(float xv){ return 1.f / (1.f + __expf(-xv)); }
__device__ __forceinline__ float ftanh(float xv){ return 1.f - 2.f / (1.f + __expf(2.f * xv)); }

// 256 blocks, 1/CU. grp = bid&7 (XCD hint), slot = bid>>3.
// Phase 1 (parallel): block bid computes Z[t=bid][512 j][32 b][4 gates] = x_t @ W_ih_t^T
//   in f32, stores **f32** (sc0sc1) — f16 Z failed absmax (R16: 3.8e-2).
//   W_ih is streamed ONCE chip-wide.
// Phase 2 (recurrence): group owns batches grp*4..+3; slot owns j = slot*16..+15.
//   Loop = poll h (XCD-local fast path, device fallback) -> LDS -> 32 MFMA -> gates
//   (+ axc cumsum of prefetched f32 Z) -> dual h-store. No W_ih traffic in loop.
__global__ __launch_bounds__(256, 1) void lstm_grp(
    const float* __restrict__ x,
    const float* __restrict__ hidden0,
    const float* __restrict__ W_hid,
    const float* __restrict__ b_hid,
    const float* __restrict__ W_ih,
    const float* __restrict__ W_hh,
    const float* __restrict__ b_ih,
    const float* __restrict__ b_hh,
    float* __restrict__ out,
    float* __restrict__ out_h0,
    unsigned* __restrict__ flags,        // [256] one-time init barrier
    float* __restrict__ Zb,              // [256 t][512 j][32 b][4 gates] f32
    unsigned short* __restrict__ hloc,   // [8][256][2048] f16-hi, plain stores
    unsigned short* __restrict__ hglb)   // [8][256][2048] f16-hi, sc0sc1 stores
{
  __shared__ unsigned short hsb[2][16 * 64 * 8];   // 2 x 16KB; rows 4..15 unused garbage

  const int tid  = threadIdx.x;
  const int bid  = blockIdx.x;
  const int grp  = bid & 7;
  const int slot = bid >> 3;
  const int lane = tid & 63;
  const int wid  = tid >> 6;               // 0..3
  const int m    = lane & 15;
  const int g    = lane >> 4;              // 0..3
  const int J0   = slot * 16;

  const int lbm   = m & 3;                 // local batch (B-frag col clamped)
  const int b_o   = grp * 4 + lbm;
  const int j_own = J0 + wid * 4 + g;
  const int R     = (m & 3) * 512 + J0 + wid * 4 + (m >> 2);
  const bool owner = (m < 4);

  unsigned short* hlg = hloc + (size_t)grp * 256 * 2048;
  unsigned short* hgg = hglb + (size_t)grp * 256 * 2048;

  // ================= Phase 1: Z producer for t = bid =================
  {
    const int tz = bid;
    const int zb = tid & 31;               // batch (global, 0..31)
    const int jq = tid >> 5;               // j-octant 0..7
    float xrow[64];
    const float* xp = x + ((size_t)zb * 256 + tz) * 64;
    #pragma unroll
    for (int d4 = 0; d4 < 16; ++d4){
      float4 f = *(const float4*)(xp + d4 * 4);
      xrow[d4*4+0] = f.x; xrow[d4*4+1] = f.y;
      xrow[d4*4+2] = f.z; xrow[d4*4+3] = f.w;
    }
    for (int jj = 0; jj < 64; ++jj){
      int j = jq * 64 + jj;
      uint32x4 zw;
      #pragma unroll
      for (int gate = 0; gate < 4; ++gate){
        const float* wp = W_ih + (size_t)(gate * 512 + j) * 16384 + (size_t)tz * 64;
        float s0 = 0.f, s1 = 0.f, s2 = 0.f, s3 = 0.f;
        #pragma unroll
        for (int d4 = 0; d4 < 16; ++d4){
          float4 w = *(const float4*)(wp + d4 * 4);
          s0 += w.x * xrow[d4*4+0];
          s1 += w.y * xrow[d4*4+1];
          s2 += w.z * xrow[d4*4+2];
          s3 += w.w * xrow[d4*4+3];
        }
        zw[gate] = __builtin_bit_cast(unsigned, (s0 + s1) + (s2 + s3));
      }
      float* zp = Zb + ((size_t)((size_t)tz * 512 + j) * 32 + zb) * 4;
      asm volatile("global_store_dwordx4 %0, %1, off sc0 sc1" :: "v"(zp), "v"(zw) : "memory");
    }
  }

  // ================= own c0/h0: exact f32 dot =================
  float c_state;
  {
    const float* hv = hidden0 + b_o * 64;
    const float* wv = W_hid + j_own * 64;
    float acc = b_hid[j_own];
    #pragma unroll
    for (int d = 0; d < 64; d += 4){
      float4 a = *(const float4*)(hv + d);
      float4 w = *(const float4*)(wv + d);
      acc += a.x*w.x + a.y*w.y + a.z*w.z + a.w*w.w;
    }
    c_state = acc;
    if (owner){
      out_h0[(size_t)b_o * 512 + j_own] = acc;
      unsigned short hh, ll; split_f16(acc, hh, ll);
      unsigned vh = hh;                    // finite => never 0xFFFF
      size_t off = (size_t)lbm * 512 + j_own;
      asm volatile("global_store_short %0, %1, off"         :: "v"(hlg + off), "v"(vh) : "memory");
      asm volatile("global_store_short %0, %1, off sc0 sc1" :: "v"(hgg + off), "v"(vh) : "memory");
    }
  }

  // ================= W_hh fragments -> registers (once) =================
  f16x8 whh_hi[16], whh_lo[16];
  #pragma unroll
  for (int kc = 0; kc < 16; ++kc){
    const float* p = W_hh + (size_t)R * 512 + kc * 32 + g * 8;
    float4 f0 = *(const float4*)p;
    float4 f1 = *(const float4*)(p + 4);
    float fs[8] = {f0.x,f0.y,f0.z,f0.w,f1.x,f1.y,f1.z,f1.w};
    short8 hb8, lb8;
    #pragma unroll
    for (int i = 0; i < 8; ++i){
      unsigned short hh, ll; split_f16(fs[i], hh, ll);
      hb8[i] = (short)hh; lb8[i] = (short)ll;
    }
    whh_hi[kc] = __builtin_bit_cast(f16x8, hb8);
    whh_lo[kc] = __builtin_bit_cast(f16x8, lb8);
  }

  const float bias_i = b_ih[j_own]        + b_hh[j_own];
  const float bias_f = b_ih[512 + j_own]  + b_hh[512 + j_own];
  const float bias_g = b_ih[1024 + j_own] + b_hh[1024 + j_own];
  const float bias_o = b_ih[1536 + j_own] + b_hh[1536 + j_own];

  // ================= one-time barrier: Z + h0 drained & visible =================
  asm volatile("s_waitcnt vmcnt(0)" ::: "memory");
  __syncthreads();
  if (tid == 0){
    unsigned one = 1;
    asm volatile("global_store_dword %0, %1, off sc0 sc1" :: "v"(flags + bid), "v"(one) : "memory");
  }
  {
    const unsigned* fp = flags + lane * 4;
    while (true){
      uint32x4 fv;
      asm volatile("global_load_dwordx4 %0, %1, off sc0 sc1\n\ts_waitcnt vmcnt(0)"
                   : "=v"(fv) : "v"(fp) : "memory");
      unsigned mn0 = fv[0] < fv[1] ? fv[0] : fv[1];
      unsigned mn1 = fv[2] < fv[3] ? fv[2] : fv[3];
      unsigned mn  = mn0 < mn1 ? mn0 : mn1;
      if (__all((int)(mn >= 1u))) break;
      __builtin_amdgcn_s_sleep(1);
    }
  }

  // ================= Phase 2: recurrence =================
  const int lb_st = tid >> 6;          // staging row (0..3)
  const int us_st = (tid & 63) ^ (lb_st & 7);
  bool use_local = true;

  // Z cumsum state; prefetch t=0 (plain cached — written pre-barrier, deterministic).
  f32x4 axc = {0.f, 0.f, 0.f, 0.f};
  f32x4 zc = *(const f32x4*)(Zb + ((size_t)((size_t)0 * 512 + j_own) * 32 + b_o) * 4);

  for (int t = 0; t < 256; ++t){
    // ---- prefetch Z(t+1): in flight across poll + MFMA ----
    f32x4 zn;
    if (t < 255)
      zn = *(const f32x4*)(Zb + ((size_t)((size_t)(t+1) * 512 + j_own) * 32 + b_o) * 4);

    uint32x4 dv;
    bool got = false;

    // ---- fast path: poll group-local copy (sc0, L2-scope), bounded ----
    if (use_local){
      const unsigned* p = (const unsigned*)(hlg + (size_t)t * 2048) + (size_t)tid * 4;
      int tries = 0;
      while (tries < 64){
        asm volatile("global_load_dwordx4 %0, %1, off sc0\n\ts_waitcnt vmcnt(0)"
                     : "=v"(dv) : "v"(p) : "memory");
        int bad = 0;
        #pragma unroll
        for (int q = 0; q < 4; ++q){
          unsigned w = dv[q];
          bad |= ((w & 0xFFFFu) == 0xFFFFu) | (w >= 0xFFFF0000u);
        }
        if (!__any(bad)){ got = true; break; }
        __builtin_amdgcn_s_sleep(1);
        ++tries;
      }
      if (!got) use_local = false;       // sticky fallback
    }
    // ---- fallback: device-scope copy (always written) ----
    if (!got){
      const unsigned* p = (const unsigned*)(hgg + (size_t)t * 2048) + (size_t)tid * 4;
      while (true){
        asm volatile("global_load_dwordx4 %0, %1, off sc0 sc1\n\ts_waitcnt vmcnt(0)"
                     : "=v"(dv) : "v"(p) : "memory");
        int bad = 0;
        #pragma unroll
        for (int q = 0; q < 4; ++q){
          unsigned w = dv[q];
          bad |= ((w & 0xFFFFu) == 0xFFFFu) | (w >= 0xFFFF0000u);
        }
        if (!__any(bad)) break;
        __builtin_amdgcn_s_sleep(1);
      }
    }

    // ---- stage 4KB tile -> swizzled LDS, buffer t&1 ----
    *(uint32x4*)(&hsb[t & 1][(size_t)(lb_st * 64 + us_st) * 8]) = dv;
    __syncthreads();   // the ONLY barrier per step

    // ---- h @ W_hh^T via MFMA (2-term W split, h hi-plane) ----
    f32x4 acc0 = {0.f,0.f,0.f,0.f}, acc2 = acc0;
    {
      const unsigned short* srcH = &hsb[t & 1][0];
      #pragma unroll
      for (int kc = 0; kc < 16; ++kc){
        int us = (kc * 4 + g) ^ (m & 7);
        f16x8 bhi = __builtin_bit_cast(f16x8, *(const short8*)(srcH + (size_t)(m * 64 + us) * 8));
        acc0 = __builtin_amdgcn_mfma_f32_16x16x32_f16(whh_hi[kc], bhi, acc0, 0,0,0);
        acc2 = __builtin_amdgcn_mfma_f32_16x16x32_f16(whh_lo[kc], bhi, acc2, 0,0,0);
      }
    }

    // ---- Z cumsum (f32 exact) + gates in-thread; owners dual-store h(t+1) ----
    axc += zc;

    f32x4 pre = acc0 + acc2 + axc;
    float ig = fsig(pre[0] + bias_i);
    float fg = fsig(pre[1] + bias_f);
    float gg = ftanh(pre[2] + bias_g);
    float og = fsig(pre[3] + bias_o);
    c_state = fg * c_state + ig * gg;
    float hval = og * ftanh(c_state);

    if (owner){
      if (t < 255){
        unsigned short hh, ll; split_f16(hval, hh, ll);
        unsigned vh = hh;                              // finite => never 0xFFFF
        size_t off = (size_t)(t+1) * 2048 + (size_t)lbm * 512 + j_own;
        asm volatile("global_store_short %0, %1, off"         :: "v"(hlg + off), "v"(vh) : "memory");
        asm volatile("global_store_short %0, %1, off sc0 sc1" :: "v"(hgg + off), "v"(vh) : "memory");
      }
      out[((size_t)b_o * 256 + t) * 512 + j_own] = fmaxf(hval, 0.f);
    }

    zc = zn;
  }
}

// ---------------------------------------------------------------------------
extern "C" void kernel_launch(void* const* d_in, const int* in_sizes, int n_in,
                              void* d_out, int out_size, void* d_ws, size_t ws_size,
                              hipStream_t stream) {
  const float* x       = (const float*)d_in[0];
  const float* hidden0 = (const float*)d_in[1];
  const float* W_hid   = (const float*)d_in[2];
  const float* b_hid   = (const float*)d_in[3];
  const float* W_ih    = (const float*)d_in[4];
  const float* W_hh    = (const float*)d_in[5];
  const float* b_ih    = (const float*)d_in[6];
  const float* b_hh    = (const float*)d_in[7];

  float* out    = (float*)d_out;
  float* out_h0 = out + (size_t)32 * 256 * 512;

  char* ws = (char*)d_ws;
  unsigned*       flags = (unsigned*)ws;                            // 1 KB
  float*          Zb    = (float*)(ws + 4096);                      // 64 MB: [256][512][32][4] f32
  unsigned short* hloc  = (unsigned short*)(ws + 4096 + (64u<<20)); // 8 MB
  unsigned short* hglb  = (unsigned short*)(ws + 4096 + (72u<<20)); // 8 MB

  (void)hipMemsetAsync(ws, 0, 4096, stream);
  (void)hipMemsetAsync(hloc, 0xFF, (size_t)8 * 256 * 2048 * 2, stream);
  (void)hipMemsetAsync(hglb, 0xFF, (size_t)8 * 256 * 2048 * 2, stream);

  lstm_grp<<<256, 256, 0, stream>>>(
      x, hidden0, W_hid, b_hid, W_ih, W_hh, b_ih, b_hh,
      out, out_h0, flags, Zb, hloc, hglb);
}

// Round 18
// 636.779 us; speedup vs baseline: 1.1680x; 1.1680x over previous
//
#include <hip/hip_runtime.h>
#include <math.h>

typedef __attribute__((ext_vector_type(8))) short short8;
typedef __attribute__((ext_vector_type(8))) _Float16 f16x8;
typedef __attribute__((ext_vector_type(4))) float f32x4;
typedef __attribute__((ext_vector_type(4))) unsigned uint32x4;

__device__ __forceinline__ void split_f16(float f, unsigned short& h, unsigned short& l){
  _Float16 hh = (_Float16)f;
  _Float16 ll = (_Float16)(f - (float)hh);
  h = __builtin_bit_cast(unsigned short, hh);
  l = __builtin_bit_cast(unsigned short, ll);
}

__device__ __forceinline__ float fsig(float xv){ return 1.f / (1.f + __expf(-xv)); }
__device__ __forceinline__ float ftanh(float xv){ return 1.f - 2.f / (1.f + __expf(2.f * xv)); }

// 256 blocks, 1/CU. grp = bid&7 (XCD hint), slot = bid>>3.
// Phase 1: Z[t=bid] = x_t @ W_ih_t^T in f32 (W_ih streamed once chip-wide).
// Phase 2: recurrence; h exchange tile is PACKED [32 slot][4 lb][16 jl] f16 —
//   each block contributes 128 contiguous bytes via 8 dwordx4 stores (LDS pack),
//   dual-written (plain->local L2 + sc0sc1->device mirror). Consumers poll the
//   local copy (sc0), sticky-fallback to the device mirror. 0xFFFF sentinel.
__global__ __launch_bounds__(256, 1) void lstm_grp(
    const float* __restrict__ x,
    const float* __restrict__ hidden0,
    const float* __restrict__ W_hid,
    const float* __restrict__ b_hid,
    const float* __restrict__ W_ih,
    const float* __restrict__ W_hh,
    const float* __restrict__ b_ih,
    const float* __restrict__ b_hh,
    float* __restrict__ out,
    float* __restrict__ out_h0,
    unsigned* __restrict__ flags,        // [256] one-time init barrier
    float* __restrict__ Zb,              // [256 t][512 j][32 b][4 gates] f32
    unsigned short* __restrict__ hloc,   // [8][256][2048] packed tiles, plain stores
    unsigned short* __restrict__ hglb)   // [8][256][2048] packed tiles, sc0sc1 stores
{
  __shared__ unsigned short hsb[2][16 * 64 * 8];   // 2 x 16KB; rows 4..15 garbage (discarded C cols)
  __shared__ unsigned short hpk[64];               // pack buffer [4 lb][16 jl]

  const int tid  = threadIdx.x;
  const int bid  = blockIdx.x;
  const int grp  = bid & 7;
  const int slot = bid >> 3;
  const int lane = tid & 63;
  const int wid  = tid >> 6;               // 0..3
  const int m    = lane & 15;
  const int g    = lane >> 4;              // 0..3
  const int J0   = slot * 16;

  const int lbm   = m & 3;                 // local batch
  const int b_o   = grp * 4 + lbm;
  const int j_own = J0 + wid * 4 + g;
  const int R     = (m & 3) * 512 + J0 + wid * 4 + (m >> 2);
  const bool owner = (m < 4);

  unsigned short* hlg = hloc + (size_t)grp * 256 * 2048;
  unsigned short* hgg = hglb + (size_t)grp * 256 * 2048;

  // ================= Phase 1: Z producer for t = bid =================
  {
    const int tz = bid;
    const int zb = tid & 31;               // batch (global)
    const int jq = tid >> 5;               // j-octant
    float xrow[64];
    const float* xp = x + ((size_t)zb * 256 + tz) * 64;
    #pragma unroll
    for (int d4 = 0; d4 < 16; ++d4){
      float4 f = *(const float4*)(xp + d4 * 4);
      xrow[d4*4+0] = f.x; xrow[d4*4+1] = f.y;
      xrow[d4*4+2] = f.z; xrow[d4*4+3] = f.w;
    }
    for (int jj = 0; jj < 64; ++jj){
      int j = jq * 64 + jj;
      uint32x4 zw;
      #pragma unroll
      for (int gate = 0; gate < 4; ++gate){
        const float* wp = W_ih + (size_t)(gate * 512 + j) * 16384 + (size_t)tz * 64;
        float s0 = 0.f, s1 = 0.f, s2 = 0.f, s3 = 0.f;
        #pragma unroll
        for (int d4 = 0; d4 < 16; ++d4){
          float4 w = *(const float4*)(wp + d4 * 4);
          s0 += w.x * xrow[d4*4+0];
          s1 += w.y * xrow[d4*4+1];
          s2 += w.z * xrow[d4*4+2];
          s3 += w.w * xrow[d4*4+3];
        }
        zw[gate] = __builtin_bit_cast(unsigned, (s0 + s1) + (s2 + s3));
      }
      float* zp = Zb + ((size_t)((size_t)tz * 512 + j) * 32 + zb) * 4;
      asm volatile("global_store_dwordx4 %0, %1, off sc0 sc1" :: "v"(zp), "v"(zw) : "memory");
    }
  }

  // ================= own c0/h0 exact f32; pack h0 into LDS =================
  float c_state;
  {
    const float* hv = hidden0 + b_o * 64;
    const float* wv = W_hid + j_own * 64;
    float acc = b_hid[j_own];
    #pragma unroll
    for (int d = 0; d < 64; d += 4){
      float4 a = *(const float4*)(hv + d);
      float4 w = *(const float4*)(wv + d);
      acc += a.x*w.x + a.y*w.y + a.z*w.z + a.w*w.w;
    }
    c_state = acc;
    if (owner){
      out_h0[(size_t)b_o * 512 + j_own] = acc;
      unsigned short hh, ll; split_f16(acc, hh, ll);
      hpk[m * 16 + wid * 4 + g] = hh;      // finite => never 0xFFFF
    }
  }

  // ================= W_hh fragments -> registers (once) =================
  f16x8 whh_hi[16], whh_lo[16];
  #pragma unroll
  for (int kc = 0; kc < 16; ++kc){
    const float* p = W_hh + (size_t)R * 512 + kc * 32 + g * 8;
    float4 f0 = *(const float4*)p;
    float4 f1 = *(const float4*)(p + 4);
    float fs[8] = {f0.x,f0.y,f0.z,f0.w,f1.x,f1.y,f1.z,f1.w};
    short8 hb8, lb8;
    #pragma unroll
    for (int i = 0; i < 8; ++i){
      unsigned short hh, ll; split_f16(fs[i], hh, ll);
      hb8[i] = (short)hh; lb8[i] = (short)ll;
    }
    whh_hi[kc] = __builtin_bit_cast(f16x8, hb8);
    whh_lo[kc] = __builtin_bit_cast(f16x8, lb8);
  }

  const float bias_i = b_ih[j_own]        + b_hh[j_own];
  const float bias_f = b_ih[512 + j_own]  + b_hh[512 + j_own];
  const float bias_g = b_ih[1024 + j_own] + b_hh[1024 + j_own];
  const float bias_o = b_ih[1536 + j_own] + b_hh[1536 + j_own];

  // ================= pack-store h0 tile, then barrier =================
  __syncthreads();                        // hpk populated
  if (tid < 8){
    uint32x4 pk = *(const uint32x4*)(hpk + tid * 8);
    unsigned short* d0 = hlg + (size_t)slot * 128 / 2 + tid * 8;   // tile 0
    unsigned short* d1 = hgg + (size_t)slot * 128 / 2 + tid * 8;
    asm volatile("global_store_dwordx4 %0, %1, off"         :: "v"(d0), "v"(pk) : "memory");
    asm volatile("global_store_dwordx4 %0, %1, off sc0 sc1" :: "v"(d1), "v"(pk) : "memory");
  }
  asm volatile("s_waitcnt vmcnt(0)" ::: "memory");
  __syncthreads();
  if (tid == 0){
    unsigned one = 1;
    asm volatile("global_store_dword %0, %1, off sc0 sc1" :: "v"(flags + bid), "v"(one) : "memory");
  }
  {
    const unsigned* fp = flags + lane * 4;
    while (true){
      uint32x4 fv;
      asm volatile("global_load_dwordx4 %0, %1, off sc0 sc1\n\ts_waitcnt vmcnt(0)"
                   : "=v"(fv) : "v"(fp) : "memory");
      unsigned mn0 = fv[0] < fv[1] ? fv[0] : fv[1];
      unsigned mn1 = fv[2] < fv[3] ? fv[2] : fv[3];
      unsigned mn  = mn0 < mn1 ? mn0 : mn1;
      if (__all((int)(mn >= 1u))) break;
      __builtin_amdgcn_s_sleep(1);
    }
  }

  // ================= Phase 2: recurrence =================
  // consumer staging decode: thread tid reads 16B at tile + tid*16
  const int sl_src = tid >> 3;
  const int r8     = tid & 7;
  const int lb_c   = r8 >> 1;              // row 0..3
  const int u_c    = sl_src * 2 + (r8 & 1);// unit 0..63
  const int us_c   = u_c ^ lb_c;           // write swizzle (matches read us=(kc*4+g)^(m&7))
  bool use_local = true;

  f32x4 axc = {0.f, 0.f, 0.f, 0.f};
  f32x4 zc = *(const f32x4*)(Zb + ((size_t)((size_t)0 * 512 + j_own) * 32 + b_o) * 4);

  for (int t = 0; t < 256; ++t){
    // ---- prefetch Z(t+1) ----
    f32x4 zn;
    if (t < 255)
      zn = *(const f32x4*)(Zb + ((size_t)((size_t)(t+1) * 512 + j_own) * 32 + b_o) * 4);

    uint32x4 dv;
    bool got = false;

    // ---- fast path: poll group-local packed tile (sc0) ----
    if (use_local){
      const unsigned* p = (const unsigned*)(hlg + (size_t)t * 2048) + (size_t)tid * 4;
      int tries = 0;
      while (tries < 64){
        asm volatile("global_load_dwordx4 %0, %1, off sc0\n\ts_waitcnt vmcnt(0)"
                     : "=v"(dv) : "v"(p) : "memory");
        int bad = 0;
        #pragma unroll
        for (int q = 0; q < 4; ++q){
          unsigned w = dv[q];
          bad |= ((w & 0xFFFFu) == 0xFFFFu) | (w >= 0xFFFF0000u);
        }
        if (!__any(bad)){ got = true; break; }
        __builtin_amdgcn_s_sleep(1);
        ++tries;
      }
      if (!got) use_local = false;       // cross-XCD pair: local can NEVER succeed -> sticky
    }
    // ---- fallback: device-scope mirror ----
    if (!got){
      const unsigned* p = (const unsigned*)(hgg + (size_t)t * 2048) + (size_t)tid * 4;
      while (true){
        asm volatile("global_load_dwordx4 %0, %1, off sc0 sc1\n\ts_waitcnt vmcnt(0)"
                     : "=v"(dv) : "v"(p) : "memory");
        int bad = 0;
        #pragma unroll
        for (int q = 0; q < 4; ++q){
          unsigned w = dv[q];
          bad |= ((w & 0xFFFFu) == 0xFFFFu) | (w >= 0xFFFF0000u);
        }
        if (!__any(bad)) break;
        __builtin_amdgcn_s_sleep(1);
      }
    }

    // ---- stage packed tile -> swizzled LDS rows 0..3, buffer t&1 ----
    *(uint32x4*)(&hsb[t & 1][(size_t)(lb_c * 64 + us_c) * 8]) = dv;
    __syncthreads();   // barrier #1

    // ---- h @ W_hh^T via MFMA (2-term W split, h hi-plane) ----
    f32x4 acc0 = {0.f,0.f,0.f,0.f}, acc2 = acc0;
    {
      const unsigned short* srcH = &hsb[t & 1][0];
      #pragma unroll
      for (int kc = 0; kc < 16; ++kc){
        int us = (kc * 4 + g) ^ (m & 7);
        f16x8 bhi = __builtin_bit_cast(f16x8, *(const short8*)(srcH + (size_t)(m * 64 + us) * 8));
        acc0 = __builtin_amdgcn_mfma_f32_16x16x32_f16(whh_hi[kc], bhi, acc0, 0,0,0);
        acc2 = __builtin_amdgcn_mfma_f32_16x16x32_f16(whh_lo[kc], bhi, acc2, 0,0,0);
      }
    }

    // ---- Z cumsum + gates; owners drop h(t+1) into pack LDS ----
    axc += zc;
    f32x4 pre = acc0 + acc2 + axc;
    float ig = fsig(pre[0] + bias_i);
    float fg = fsig(pre[1] + bias_f);
    float gg = ftanh(pre[2] + bias_g);
    float og = fsig(pre[3] + bias_o);
    c_state = fg * c_state + ig * gg;
    float hval = og * ftanh(c_state);

    if (owner){
      unsigned short hh, ll; split_f16(hval, hh, ll);
      hpk[m * 16 + wid * 4 + g] = hh;      // finite => never 0xFFFF
      out[((size_t)b_o * 256 + t) * 512 + j_own] = fmaxf(hval, 0.f);
    }
    __syncthreads();   // barrier #2: hpk complete

    // ---- 8 wide stores publish the block's 128B contribution ----
    if (t < 255 && tid < 8){
      uint32x4 pk = *(const uint32x4*)(hpk + tid * 8);
      unsigned short* d0 = hlg + (size_t)(t+1) * 2048 + (size_t)slot * 64 + tid * 8;
      unsigned short* d1 = hgg + (size_t)(t+1) * 2048 + (size_t)slot * 64 + tid * 8;
      asm volatile("global_store_dwordx4 %0, %1, off"         :: "v"(d0), "v"(pk) : "memory");
      asm volatile("global_store_dwordx4 %0, %1, off sc0 sc1" :: "v"(d1), "v"(pk) : "memory");
    }

    zc = zn;
  }
}

// ---------------------------------------------------------------------------
extern "C" void kernel_launch(void* const* d_in, const int* in_sizes, int n_in,
                              void* d_out, int out_size, void* d_ws, size_t ws_size,
                              hipStream_t stream) {
  const float* x       = (const float*)d_in[0];
  const float* hidden0 = (const float*)d_in[1];
  const float* W_hid   = (const float*)d_in[2];
  const float* b_hid   = (const float*)d_in[3];
  const float* W_ih    = (const float*)d_in[4];
  const float* W_hh    = (const float*)d_in[5];
  const float* b_ih    = (const float*)d_in[6];
  const float* b_hh    = (const float*)d_in[7];

  float* out    = (float*)d_out;
  float* out_h0 = out + (size_t)32 * 256 * 512;

  char* ws = (char*)d_ws;
  unsigned*       flags = (unsigned*)ws;                            // 1 KB
  float*          Zb    = (float*)(ws + 4096);                      // 64 MB
  unsigned short* hloc  = (unsigned short*)(ws + 4096 + (64u<<20)); // 8 MB (packed tiles)
  unsigned short* hglb  = (unsigned short*)(ws + 4096 + (72u<<20)); // 8 MB

  (void)hipMemsetAsync(ws, 0, 4096, stream);
  (void)hipMemsetAsync(hloc, 0xFF, (size_t)8 * 256 * 2048 * 2, stream);
  (void)hipMemsetAsync(hglb, 0xFF, (size_t)8 * 256 * 2048 * 2, stream);

  lstm_grp<<<256, 256, 0, stream>>>(
      x, hidden0, W_hid, b_hid, W_ih, W_hh, b_ih, b_hh,
      out, out_h0, flags, Zb, hloc, hglb);
}